// Round 1
// baseline (1237.639 us; speedup 1.0000x reference)
//
#include <hip/hip_runtime.h>
#include <stdint.h>

typedef unsigned short u16;
typedef __bf16 bf16x8 __attribute__((ext_vector_type(8)));
typedef float f32x4 __attribute__((ext_vector_type(4)));

#define HID 512
#define BATCH 32
#define SEQ 2048
#define NLAYERS 4
#define BT (BATCH*SEQ)
#define CHUNKS 64
#define TC (SEQ/CHUNKS)

__device__ __forceinline__ float bf2f(uint32_t lo) {
  union { uint32_t u; float f; } c; c.u = lo << 16; return c.f;
}
__device__ __forceinline__ uint32_t f2bf(float f) {
  union { float f; uint32_t u; } c; c.f = f;
  return (c.u + 0x7fffu + ((c.u >> 16) & 1u)) >> 16;  // RNE
}
__device__ __forceinline__ float fast_rcp(float x) { return __builtin_amdgcn_rcpf(x); }

// async global->LDS, 16B per lane; LDS dest must be wave-uniform base (lane*16 implicit)
__device__ __forceinline__ void gload_lds16(const u16* g, u16* l) {
  __builtin_amdgcn_global_load_lds((__attribute__((address_space(1))) void*)g,
                                   (__attribute__((address_space(3))) void*)l, 16, 0, 0);
}

// ---------------- weight transpose+convert: Wt[l][n][k] = (n<512?Wz:Wh)[l][k][n%512], bf16
__global__ __launch_bounds__(256) void conv_weights(const float* __restrict__ Wz,
                                                    const float* __restrict__ Wh,
                                                    u16* __restrict__ Wt) {
  __shared__ float tile[64][65];
  const int l = blockIdx.z;
  const int k0 = blockIdx.x * 64;        // 0..448
  const int n0 = blockIdx.y * 64;        // 0..960
  const float* W = (n0 < 512 ? Wz : Wh) + (size_t)l * HID * HID;
  const int nc0 = (n0 < 512) ? n0 : n0 - 512;
  const int tx = threadIdx.x & 63, ty = threadIdx.x >> 6;
  for (int r = ty; r < 64; r += 4) tile[r][tx] = W[(size_t)(k0 + r) * HID + nc0 + tx];
  __syncthreads();
  for (int r = ty; r < 64; r += 4)
    Wt[((size_t)l * 1024 + n0 + r) * HID + k0 + tx] = (u16)f2bf(tile[tx][r]);
}

// ---------------- x -> bf16
__global__ __launch_bounds__(256) void conv_x(const float* __restrict__ x, u16* __restrict__ xb) {
  size_t i = ((size_t)blockIdx.x * 256 + threadIdx.x) * 4;
  float4 f = *(const float4*)(x + i);
  uint2 o;
  o.x = f2bf(f.x) | (f2bf(f.y) << 16);
  o.y = f2bf(f.z) | (f2bf(f.w) << 16);
  *(uint2*)(xb + i) = o;
}

// ---------------- fused GEMM: [k | hh] = cur @ [Wz | Wh] + bias, epilogue -> packed (a,v) bf16
// block: 256 thr (4 waves), tile 128(m) x 128(n: 64 Wz-cols + 64 Wh-cols, same h range)
__global__ __launch_bounds__(256) void gemm_av(const u16* __restrict__ Ab,
                                               const u16* __restrict__ Btw,
                                               const float* __restrict__ bz,
                                               const float* __restrict__ bh,
                                               uint32_t* __restrict__ av) {
  __shared__ u16 As[128 * 32];   // [m][k], 64B rows
  __shared__ u16 Bs[128 * 32];   // [n][k]; n<64 -> Wz col hb*64+n, n>=64 -> Wh col hb*64+n-64
  const int hb = blockIdx.x;             // 0..7
  const int m0 = blockIdx.y * 128;       // 0..65408
  const int tid = threadIdx.x;
  const int lane = tid & 63;
  const int wv = tid >> 6;

  f32x4 acc[2][8];
#pragma unroll
  for (int i = 0; i < 2; ++i)
#pragma unroll
    for (int j = 0; j < 8; ++j) acc[i][j] = (f32x4){0.f, 0.f, 0.f, 0.f};

  // staging address per lane: 16 rows per wave-instr, 4 lanes per 64B row
  const int srow = wv * 32 + (lane >> 2);
  const int skoff = (lane & 3) * 8;
  const u16* gA = Ab + (size_t)(m0 + srow) * HID + skoff;
  const int nn = srow;  // wave-uniform branch: waves 0,1 stage Wz cols, waves 2,3 Wh cols
  const int brow = (nn < 64) ? (hb * 64 + nn) : (448 + hb * 64 + nn);
  const u16* gB = Btw + (size_t)brow * HID + skoff;

  for (int kk = 0; kk < HID; kk += 32) {
#pragma unroll
    for (int j = 0; j < 2; ++j) {
      gload_lds16(gA + (size_t)(j * 16) * HID + kk, &As[(wv * 32 + j * 16) * 32]);
      gload_lds16(gB + (size_t)(j * 16) * HID + kk, &Bs[(wv * 32 + j * 16) * 32]);
    }
    __syncthreads();  // drains vmcnt(0) before barrier
    bf16x8 af[2], bfr[8];
#pragma unroll
    for (int i = 0; i < 2; ++i)
      af[i] = *(const bf16x8*)&As[(wv * 32 + i * 16 + (lane & 15)) * 32 + (lane >> 4) * 8];
#pragma unroll
    for (int j = 0; j < 8; ++j)
      bfr[j] = *(const bf16x8*)&Bs[(j * 16 + (lane & 15)) * 32 + (lane >> 4) * 8];
#pragma unroll
    for (int i = 0; i < 2; ++i)
#pragma unroll
      for (int j = 0; j < 8; ++j)
        acc[i][j] = __builtin_amdgcn_mfma_f32_16x16x32_bf16(af[i], bfr[j], acc[i][j], 0, 0, 0);
    __syncthreads();
  }

  // epilogue: C/D layout col=lane&15, row=quad*4+reg. acc[i][jj]=k, acc[i][jj+4]=hh (same h!)
  const int col0 = hb * 64 + (lane & 15);
  const int quad = lane >> 4;
  float bzv[4], bhv[4];
#pragma unroll
  for (int jj = 0; jj < 4; ++jj) { bzv[jj] = bz[col0 + jj * 16]; bhv[jj] = bh[col0 + jj * 16]; }
#pragma unroll
  for (int i = 0; i < 2; ++i) {
    const int rbase = m0 + wv * 32 + i * 16 + quad * 4;
#pragma unroll
    for (int jj = 0; jj < 4; ++jj) {
#pragma unroll
      for (int r = 0; r < 4; ++r) {
        float kv = acc[i][jj][r] + bzv[jj];
        float hv = acc[i][jj + 4][r] + bhv[jj];
        float e = __expf(-kv);
        float inv = fast_rcp(1.f + e);
        float a = e * inv;   // sigmoid(-k) = 1-z
        float z = inv;       // sigmoid(k)
        float gv = (hv >= 0.f) ? (hv + 0.5f) : fast_rcp(1.f + __expf(-hv));
        av[(size_t)(rbase + r) * HID + col0 + jj * 16] = f2bf(a) | (f2bf(z * gv) << 16);
      }
    }
  }
}

// ---------------- phase 1: per-(b,chunk,h) compose chunk transform h_out = A*h_in + B
__global__ __launch_bounds__(512) void scan_local(const uint32_t* __restrict__ av,
                                                  float* __restrict__ Ac,
                                                  float* __restrict__ Bc) {
  const int b = blockIdx.y, c = blockIdx.x, h = threadIdx.x;
  size_t base = ((size_t)(b * SEQ + c * TC)) * HID + h;
  float A = 1.f, Bv = 0.f;
#pragma unroll
  for (int t = 0; t < TC; ++t) {
    uint32_t p = av[base + (size_t)t * HID];
    float a = bf2f(p & 0xffffu), v = bf2f(p >> 16);
    A *= a;
    Bv = a * Bv + v;
  }
  size_t o = ((size_t)(b * CHUNKS + c)) * HID + h;
  Ac[o] = A;
  Bc[o] = Bv;
}

// ---------------- phase 2: sequential over chunks; also emits h[T-1] (the hiddens output)
__global__ __launch_bounds__(256) void scan_boundary(const float* __restrict__ Ac,
                                                     const float* __restrict__ Bc,
                                                     const float* __restrict__ h0,
                                                     float* __restrict__ hinit,
                                                     float* __restrict__ hid_out) {
  const int idx = blockIdx.x * 256 + threadIdx.x;  // b*HID + h
  const int b = idx >> 9, h = idx & 511;
  float x0 = h0[idx];
  float hr = (x0 >= 0.f) ? (x0 + 0.5f) : fast_rcp(1.f + __expf(-x0));  // g(h0)
  for (int c = 0; c < CHUNKS; ++c) {
    size_t o = ((size_t)(b * CHUNKS + c)) * HID + h;
    hinit[o] = hr;
    hr = Ac[o] * hr + Bc[o];
  }
  hid_out[idx] = hr;
}

// ---------------- phase 3: apply scan + LayerNorm + residual (block = one (b,chunk), 512 thr)
__global__ __launch_bounds__(512) void scan_apply(const uint32_t* av,  // no restrict: may alias outf
                                                  const float* __restrict__ hinit,
                                                  const float* resf, const u16* resb,
                                                  const float* __restrict__ gamma,
                                                  const float* __restrict__ beta,
                                                  u16* outb, float* outf) {
  __shared__ float red[2][8][2];
  const int b = blockIdx.y, c = blockIdx.x, h = threadIdx.x;
  const int lane = h & 63, wv = h >> 6;
  float hr = hinit[((size_t)(b * CHUNKS + c)) * HID + h];
  const float gm = gamma[h], be = beta[h];
  size_t base = ((size_t)(b * SEQ + c * TC)) * HID + h;
  for (int t = 0; t < TC; ++t) {
    size_t o = base + (size_t)t * HID;
    uint32_t p = av[o];
    hr = bf2f(p & 0xffffu) * hr + bf2f(p >> 16);
    float s = hr, s2 = hr * hr;
#pragma unroll
    for (int d = 32; d; d >>= 1) { s += __shfl_xor(s, d); s2 += __shfl_xor(s2, d); }
    if (lane == 0) { red[t & 1][wv][0] = s; red[t & 1][wv][1] = s2; }
    __syncthreads();
    float sum = 0.f, sum2 = 0.f;
#pragma unroll
    for (int w2 = 0; w2 < 8; ++w2) { sum += red[t & 1][w2][0]; sum2 += red[t & 1][w2][1]; }
    const float mu = sum * (1.f / HID);
    const float var = sum2 * (1.f / HID) - mu * mu;
    const float y = (hr - mu) * rsqrtf(var + 1e-5f) * gm + be;
    const float r = resf ? resf[o] : bf2f(resb[o]);
    const float outv = y + r;
    if (outb) outb[o] = (u16)f2bf(outv);
    if (outf) outf[o] = outv;
  }
}

extern "C" void kernel_launch(void* const* d_in, const int* in_sizes, int n_in,
                              void* d_out, int out_size, void* d_ws, size_t ws_size,
                              hipStream_t stream) {
  (void)in_sizes; (void)n_in; (void)out_size; (void)ws_size;
  const float* x     = (const float*)d_in[0];
  const float* h0    = (const float*)d_in[1];
  const float* Wz    = (const float*)d_in[2];
  const float* bz    = (const float*)d_in[3];
  const float* Wh    = (const float*)d_in[4];
  const float* bh    = (const float*)d_in[5];
  const float* gamma = (const float*)d_in[6];
  const float* beta  = (const float*)d_in[7];

  float* outf = (float*)d_out;                   // [BT*HID] cur, then [L*B*H] hiddens
  uint32_t* av = (uint32_t*)d_out;               // alias: cur region free until layer-3 apply

  char* ws = (char*)d_ws;
  u16* curb = (u16*)ws;                                   size_t off = (size_t)BT * HID * 2;
  u16* Wt = (u16*)(ws + off);                             off += (size_t)NLAYERS * 1024 * HID * 2;
  float* Ac = (float*)(ws + off);                         off += (size_t)BATCH * CHUNKS * HID * 4;
  float* Bc = (float*)(ws + off);                         off += (size_t)BATCH * CHUNKS * HID * 4;
  float* hinit = (float*)(ws + off);                      // + 4 MB; total ~84 MB

  hipLaunchKernelGGL(conv_weights, dim3(8, 16, NLAYERS), dim3(256), 0, stream, Wz, Wh, Wt);
  hipLaunchKernelGGL(conv_x, dim3(BT * HID / 1024), dim3(256), 0, stream, x, curb);

  for (int l = 0; l < NLAYERS; ++l) {
    const bool last = (l == NLAYERS - 1);
    hipLaunchKernelGGL(gemm_av, dim3(8, BT / 128), dim3(256), 0, stream,
                       curb, Wt + (size_t)l * 1024 * HID, bz + l * HID, bh + l * HID, av);
    hipLaunchKernelGGL(scan_local, dim3(CHUNKS, BATCH), dim3(512), 0, stream, av, Ac, Bc);
    hipLaunchKernelGGL(scan_boundary, dim3(BATCH * HID / 256), dim3(256), 0, stream,
                       Ac, Bc, h0 + (size_t)l * BATCH * HID, hinit,
                       outf + (size_t)BT * HID + (size_t)l * BATCH * HID);
    hipLaunchKernelGGL(scan_apply, dim3(CHUNKS, BATCH), dim3(512), 0, stream,
                       av, hinit,
                       (l == 0) ? x : nullptr, (l == 0) ? nullptr : curb,
                       gamma + l * HID, beta + l * HID,
                       last ? nullptr : curb, last ? outf : nullptr);
  }
}

// Round 2
// 1106.163 us; speedup vs baseline: 1.1189x; 1.1189x over previous
//
#include <hip/hip_runtime.h>
#include <stdint.h>

typedef unsigned short u16;
typedef __bf16 bf16x8 __attribute__((ext_vector_type(8)));
typedef float f32x4 __attribute__((ext_vector_type(4)));

#define HID 512
#define BATCH 32
#define SEQ 2048
#define NLAYERS 4
#define BT (BATCH*SEQ)
#define CHUNKS 64
#define TC (SEQ/CHUNKS)

__device__ __forceinline__ float bf2f(uint32_t lo) {
  union { uint32_t u; float f; } c; c.u = lo << 16; return c.f;
}
__device__ __forceinline__ uint32_t f2bf(float f) {
  union { float f; uint32_t u; } c; c.f = f;
  return (c.u + 0x7fffu + ((c.u >> 16) & 1u)) >> 16;  // RNE
}
__device__ __forceinline__ float fast_rcp(float x) { return __builtin_amdgcn_rcpf(x); }

// async global->LDS, 16B per lane; LDS dest is wave-uniform base + lane*16
__device__ __forceinline__ void gload_lds16(const u16* g, u16* l) {
  __builtin_amdgcn_global_load_lds((__attribute__((address_space(1))) void*)g,
                                   (__attribute__((address_space(3))) void*)l, 16, 0, 0);
}

// ---------------- weight transpose+convert: Wt[l][n][k] = (n<512?Wz:Wh)[l][k][n%512], bf16
__global__ __launch_bounds__(256) void conv_weights(const float* __restrict__ Wz,
                                                    const float* __restrict__ Wh,
                                                    u16* __restrict__ Wt) {
  __shared__ float tile[64][65];
  const int l = blockIdx.z;
  const int k0 = blockIdx.x * 64;
  const int n0 = blockIdx.y * 64;
  const float* W = (n0 < 512 ? Wz : Wh) + (size_t)l * HID * HID;
  const int nc0 = (n0 < 512) ? n0 : n0 - 512;
  const int tx = threadIdx.x & 63, ty = threadIdx.x >> 6;
  for (int r = ty; r < 64; r += 4) tile[r][tx] = W[(size_t)(k0 + r) * HID + nc0 + tx];
  __syncthreads();
  for (int r = ty; r < 64; r += 4)
    Wt[((size_t)l * 1024 + n0 + r) * HID + k0 + tx] = (u16)f2bf(tile[tx][r]);
}

// ---------------- x -> bf16
__global__ __launch_bounds__(256) void conv_x(const float* __restrict__ x, u16* __restrict__ xb) {
  size_t i = ((size_t)blockIdx.x * 256 + threadIdx.x) * 4;
  float4 f = *(const float4*)(x + i);
  uint2 o;
  o.x = f2bf(f.x) | (f2bf(f.y) << 16);
  o.y = f2bf(f.z) | (f2bf(f.w) << 16);
  *(uint2*)(xb + i) = o;
}

// ---------------- fused GEMM: [k | hh] = cur @ [Wz | Wh] + bias -> packed (a,v) bf16
//                  + fused chunk-local scan composition (Ac, Bc) in the epilogue.
// block: 256 thr (4 waves), tile 128(m) x 128(n: 64 Wz-cols + 64 Wh-cols, same h range).
// LDS uses XOR-swizzled k-chunks: slot s of row r holds global 16B-chunk s ^ ((r>>1)&3),
// making every ds_read_b128 a 2-way (free) bank pattern instead of 8-way.
__global__ __launch_bounds__(256) void gemm_av(const u16* __restrict__ Ab,
                                               const u16* __restrict__ Btw,
                                               const float* __restrict__ bz,
                                               const float* __restrict__ bh,
                                               uint32_t* __restrict__ av,
                                               float* __restrict__ Ac,
                                               float* __restrict__ Bc) {
  __shared__ u16 As[128 * 32];   // [m][k-swizzled], 64B rows
  __shared__ u16 Bs[128 * 32];   // [n][k-swizzled]
  const int hb = blockIdx.x;             // 0..7
  const int m0 = blockIdx.y * 128;
  const int tid = threadIdx.x;
  const int lane = tid & 63;
  const int wv = tid >> 6;

  f32x4 acc[2][8];
#pragma unroll
  for (int i = 0; i < 2; ++i)
#pragma unroll
    for (int j = 0; j < 8; ++j) acc[i][j] = (f32x4){0.f, 0.f, 0.f, 0.f};

  // staging: 16 rows per wave-instr, 4 lanes per 64B row; swizzled source chunk
  const int srow = wv * 32 + (lane >> 2);
  const int swz_st = (((lane & 3) ^ ((lane >> 3) & 3))) * 8;   // lane-constant
  const u16* gA = Ab + (size_t)(m0 + srow) * HID + swz_st;
  const int nn = srow;  // wave-uniform: waves 0,1 stage Wz cols, waves 2,3 Wh cols
  const int brow = (nn < 64) ? (hb * 64 + nn) : (448 + hb * 64 + nn);
  const u16* gB = Btw + (size_t)brow * HID + swz_st;

  // reader offset: chunk (lane>>4) lives at slot (lane>>4) ^ ((row>>1)&3), row=..+ (lane&15)
  const int rdoff = (((lane >> 4) ^ ((lane >> 1) & 3))) * 8;   // lane-constant

  for (int kk = 0; kk < HID; kk += 32) {
#pragma unroll
    for (int j = 0; j < 2; ++j) {
      gload_lds16(gA + (size_t)(j * 16) * HID + kk, &As[(wv * 32 + j * 16) * 32]);
      gload_lds16(gB + (size_t)(j * 16) * HID + kk, &Bs[(wv * 32 + j * 16) * 32]);
    }
    __syncthreads();
    bf16x8 af[2], bfr[8];
#pragma unroll
    for (int i = 0; i < 2; ++i)
      af[i] = *(const bf16x8*)&As[(wv * 32 + i * 16 + (lane & 15)) * 32 + rdoff];
#pragma unroll
    for (int j = 0; j < 8; ++j)
      bfr[j] = *(const bf16x8*)&Bs[(j * 16 + (lane & 15)) * 32 + rdoff];
#pragma unroll
    for (int i = 0; i < 2; ++i)
#pragma unroll
      for (int j = 0; j < 8; ++j)
        acc[i][j] = __builtin_amdgcn_mfma_f32_16x16x32_bf16(af[i], bfr[j], acc[i][j], 0, 0, 0);
    __syncthreads();
  }

  // epilogue: C/D layout col=lane&15, row=quad*4+reg. acc[i][jj]=k, acc[i][jj+4]=hh.
  // wave wv owns exactly rows [m0+wv*32, +32) = one scan chunk.
  const int col0 = hb * 64 + (lane & 15);
  const int quad = lane >> 4;
  float bzv[4], bhv[4];
#pragma unroll
  for (int jj = 0; jj < 4; ++jj) { bzv[jj] = bz[col0 + jj * 16]; bhv[jj] = bh[col0 + jj * 16]; }

  const int mrow = m0 + wv * 32;
  const int bb = mrow >> 11;           // / SEQ
  const int cc = (mrow & 2047) >> 5;   // chunk within batch
  const size_t abase = ((size_t)(bb * CHUNKS + cc)) * HID;

#pragma unroll
  for (int jj = 0; jj < 4; ++jj) {
    float Aseg[2], Bseg[2];
#pragma unroll
    for (int i = 0; i < 2; ++i) {
      const int rbase = mrow + i * 16 + quad * 4;
      float A = 1.f, Bv = 0.f;
#pragma unroll
      for (int r = 0; r < 4; ++r) {
        float kv = acc[i][jj][r] + bzv[jj];
        float hv = acc[i][jj + 4][r] + bhv[jj];
        float e = __expf(-kv);
        float inv = fast_rcp(1.f + e);
        float a = e * inv;   // sigmoid(-k) = 1-z
        float v = inv * ((hv >= 0.f) ? (hv + 0.5f) : fast_rcp(1.f + __expf(-hv)));
        av[(size_t)(rbase + r) * HID + col0 + jj * 16] = f2bf(a) | (f2bf(v) << 16);
        A *= a;
        Bv = a * Bv + v;    // in-t-order fold (r ascending = t ascending)
      }
      Aseg[i] = A; Bseg[i] = Bv;
    }
    // cross-quad composition (segments ordered by quad), then i=0 before i=1
#pragma unroll
    for (int i = 0; i < 2; ++i) {
      float Ap = __shfl_xor(Aseg[i], 16), Bp = __shfl_xor(Bseg[i], 16);
      float Ae = (quad & 1) ? Ap : Aseg[i], Be = (quad & 1) ? Bp : Bseg[i];
      float Al = (quad & 1) ? Aseg[i] : Ap, Bl = (quad & 1) ? Bseg[i] : Bp;
      Aseg[i] = Al * Ae; Bseg[i] = Al * Be + Bl;
      Ap = __shfl_xor(Aseg[i], 32); Bp = __shfl_xor(Bseg[i], 32);
      Ae = (quad & 2) ? Ap : Aseg[i]; Be = (quad & 2) ? Bp : Bseg[i];
      Al = (quad & 2) ? Aseg[i] : Ap; Bl = (quad & 2) ? Bseg[i] : Bp;
      Aseg[i] = Al * Ae; Bseg[i] = Al * Be + Bl;
    }
    float CA = Aseg[1] * Aseg[0];
    float CB = Aseg[1] * Bseg[0] + Bseg[1];
    if (quad == 0) {
      Ac[abase + col0 + jj * 16] = CA;
      Bc[abase + col0 + jj * 16] = CB;
    }
  }
}

// ---------------- phase 2: sequential over chunks; also emits h[T-1] (hiddens output)
__global__ __launch_bounds__(256) void scan_boundary(const float* __restrict__ Ac,
                                                     const float* __restrict__ Bc,
                                                     const float* __restrict__ h0,
                                                     float* __restrict__ hinit,
                                                     float* __restrict__ hid_out) {
  const int idx = blockIdx.x * 256 + threadIdx.x;  // b*HID + h
  const int b = idx >> 9, h = idx & 511;
  float x0 = h0[idx];
  float hr = (x0 >= 0.f) ? (x0 + 0.5f) : fast_rcp(1.f + __expf(-x0));  // g(h0)
  for (int c = 0; c < CHUNKS; ++c) {
    size_t o = ((size_t)(b * CHUNKS + c)) * HID + h;
    hinit[o] = hr;
    hr = Ac[o] * hr + Bc[o];
  }
  hid_out[idx] = hr;
}

// ---------------- phase 3: apply scan + LayerNorm + residual (block = one (b,chunk))
// t processed in pairs: one __syncthreads per 2 steps.
__global__ __launch_bounds__(512) void scan_apply(const uint32_t* av,  // may alias outf
                                                  const float* __restrict__ hinit,
                                                  const u16* __restrict__ resb,
                                                  const float* __restrict__ gamma,
                                                  const float* __restrict__ beta,
                                                  u16* outb, float* outf) {
  __shared__ float red[2][8][4];
  const int b = blockIdx.y, c = blockIdx.x, h = threadIdx.x;
  const int lane = h & 63, wv = h >> 6;
  float hr = hinit[((size_t)(b * CHUNKS + c)) * HID + h];
  const float gm = gamma[h], be = beta[h];
  size_t base = ((size_t)(b * SEQ + c * TC)) * HID + h;
  for (int t = 0; t < TC; t += 2) {
    size_t o0 = base + (size_t)t * HID, o1 = o0 + HID;
    uint32_t p0 = av[o0], p1 = av[o1];
    float r0 = bf2f((uint32_t)resb[o0]), r1 = bf2f((uint32_t)resb[o1]);
    float h1 = bf2f(p0 & 0xffffu) * hr + bf2f(p0 >> 16);
    float h2 = bf2f(p1 & 0xffffu) * h1 + bf2f(p1 >> 16);
    hr = h2;
    float s1 = h1, s2 = h2, q1 = h1 * h1, q2 = h2 * h2;
#pragma unroll
    for (int d = 32; d; d >>= 1) {
      s1 += __shfl_xor(s1, d); q1 += __shfl_xor(q1, d);
      s2 += __shfl_xor(s2, d); q2 += __shfl_xor(q2, d);
    }
    const int tb = (t >> 1) & 1;
    if (lane == 0) { red[tb][wv][0] = s1; red[tb][wv][1] = q1; red[tb][wv][2] = s2; red[tb][wv][3] = q2; }
    __syncthreads();
    float su1 = 0.f, sq1 = 0.f, su2 = 0.f, sq2 = 0.f;
#pragma unroll
    for (int w2 = 0; w2 < 8; ++w2) {
      su1 += red[tb][w2][0]; sq1 += red[tb][w2][1];
      su2 += red[tb][w2][2]; sq2 += red[tb][w2][3];
    }
    const float mu1 = su1 * (1.f / HID), mu2 = su2 * (1.f / HID);
    const float v1 = sq1 * (1.f / HID) - mu1 * mu1, v2 = sq2 * (1.f / HID) - mu2 * mu2;
    const float y1 = (h1 - mu1) * rsqrtf(v1 + 1e-5f) * gm + be + r0;
    const float y2 = (h2 - mu2) * rsqrtf(v2 + 1e-5f) * gm + be + r1;
    if (outb) { outb[o0] = (u16)f2bf(y1); outb[o1] = (u16)f2bf(y2); }
    if (outf) { outf[o0] = y1; outf[o1] = y2; }
  }
}

extern "C" void kernel_launch(void* const* d_in, const int* in_sizes, int n_in,
                              void* d_out, int out_size, void* d_ws, size_t ws_size,
                              hipStream_t stream) {
  (void)in_sizes; (void)n_in; (void)out_size; (void)ws_size;
  const float* x     = (const float*)d_in[0];
  const float* h0    = (const float*)d_in[1];
  const float* Wz    = (const float*)d_in[2];
  const float* bz    = (const float*)d_in[3];
  const float* Wh    = (const float*)d_in[4];
  const float* bh    = (const float*)d_in[5];
  const float* gamma = (const float*)d_in[6];
  const float* beta  = (const float*)d_in[7];

  float* outf = (float*)d_out;                   // [BT*HID] cur, then [L*B*H] hiddens
  uint32_t* av = (uint32_t*)d_out;               // alias: cur region free until last apply

  char* ws = (char*)d_ws;
  u16* curb = (u16*)ws;                                   size_t off = (size_t)BT * HID * 2;
  u16* Wt = (u16*)(ws + off);                             off += (size_t)NLAYERS * 1024 * HID * 2;
  float* Ac = (float*)(ws + off);                         off += (size_t)BATCH * CHUNKS * HID * 4;
  float* Bc = (float*)(ws + off);                         off += (size_t)BATCH * CHUNKS * HID * 4;
  float* hinit = (float*)(ws + off);                      // total ~80 MB

  hipLaunchKernelGGL(conv_weights, dim3(8, 16, NLAYERS), dim3(256), 0, stream, Wz, Wh, Wt);
  hipLaunchKernelGGL(conv_x, dim3(BT * HID / 1024), dim3(256), 0, stream, x, curb);

  for (int l = 0; l < NLAYERS; ++l) {
    const bool last = (l == NLAYERS - 1);
    hipLaunchKernelGGL(gemm_av, dim3(8, BT / 128), dim3(256), 0, stream,
                       curb, Wt + (size_t)l * 1024 * HID, bz + l * HID, bh + l * HID,
                       av, Ac, Bc);
    hipLaunchKernelGGL(scan_boundary, dim3(BATCH * HID / 256), dim3(256), 0, stream,
                       Ac, Bc, h0 + (size_t)l * BATCH * HID, hinit,
                       outf + (size_t)BT * HID + (size_t)l * BATCH * HID);
    hipLaunchKernelGGL(scan_apply, dim3(CHUNKS, BATCH), dim3(512), 0, stream,
                       av, hinit, curb, gamma + l * HID, beta + l * HID,
                       last ? nullptr : curb, last ? outf : nullptr);
  }
}

// Round 3
// 832.940 us; speedup vs baseline: 1.4859x; 1.3280x over previous
//
#include <hip/hip_runtime.h>
#include <stdint.h>

typedef unsigned short u16;
typedef __bf16 bf16x8 __attribute__((ext_vector_type(8)));
typedef float f32x4 __attribute__((ext_vector_type(4)));

#define HID 512
#define BATCH 32
#define SEQ 2048
#define NLAYERS 4
#define BT (BATCH*SEQ)
#define CHUNKS 64
#define TC (SEQ/CHUNKS)

__device__ __forceinline__ float bf2f(uint32_t lo) {
  union { uint32_t u; float f; } c; c.u = lo << 16; return c.f;
}
__device__ __forceinline__ uint32_t f2bf(float f) {
  union { float f; uint32_t u; } c; c.f = f;
  return (c.u + 0x7fffu + ((c.u >> 16) & 1u)) >> 16;  // RNE
}
__device__ __forceinline__ float fast_rcp(float x) { return __builtin_amdgcn_rcpf(x); }

// async global->LDS, 16B per lane; LDS dest is wave-uniform base + lane*16
__device__ __forceinline__ void gload_lds16(const u16* g, u16* l) {
  __builtin_amdgcn_global_load_lds((__attribute__((address_space(1))) void*)g,
                                   (__attribute__((address_space(3))) void*)l, 16, 0, 0);
}

// ---------------- weight transpose+convert: Wt[l][n][k] = (n<512?Wz:Wh)[l][k][n%512], bf16
__global__ __launch_bounds__(256) void conv_weights(const float* __restrict__ Wz,
                                                    const float* __restrict__ Wh,
                                                    u16* __restrict__ Wt) {
  __shared__ float tile[64][65];
  const int l = blockIdx.z;
  const int k0 = blockIdx.x * 64;
  const int n0 = blockIdx.y * 64;
  const float* W = (n0 < 512 ? Wz : Wh) + (size_t)l * HID * HID;
  const int nc0 = (n0 < 512) ? n0 : n0 - 512;
  const int tx = threadIdx.x & 63, ty = threadIdx.x >> 6;
  for (int r = ty; r < 64; r += 4) tile[r][tx] = W[(size_t)(k0 + r) * HID + nc0 + tx];
  __syncthreads();
  for (int r = ty; r < 64; r += 4)
    Wt[((size_t)l * 1024 + n0 + r) * HID + k0 + tx] = (u16)f2bf(tile[tx][r]);
}

// ---------------- x -> bf16
__global__ __launch_bounds__(256) void conv_x(const float* __restrict__ x, u16* __restrict__ xb) {
  size_t i = ((size_t)blockIdx.x * 256 + threadIdx.x) * 4;
  float4 f = *(const float4*)(x + i);
  uint2 o;
  o.x = f2bf(f.x) | (f2bf(f.y) << 16);
  o.y = f2bf(f.z) | (f2bf(f.w) << 16);
  *(uint2*)(xb + i) = o;
}

// ---------------- fused GEMM: [k | hh] = cur @ [Wz | Wh] + bias -> packed (a,v) bf16
//                  + fused chunk-local scan composition (Ac, Bc) in the epilogue.
// 1D grid, XCD-swizzled: all 8 hb-blocks of one m-tile get ids == same (mod 8) inside a
// 64-block window -> same XCD L2 -> A-tile fetched from HBM once, not 8x.
__global__ __launch_bounds__(256) void gemm_av(const u16* __restrict__ Ab,
                                               const u16* __restrict__ Btw,
                                               const float* __restrict__ bz,
                                               const float* __restrict__ bh,
                                               uint32_t* __restrict__ av,
                                               float* __restrict__ Ac,
                                               float* __restrict__ Bc) {
  __shared__ u16 As[128 * 32];   // [m][k-swizzled], 64B rows
  __shared__ u16 Bs[128 * 32];   // [n][k-swizzled]
  const int blk = blockIdx.x;
  const int sub = blk & 63;
  const int hb = sub >> 3;                       // 0..7
  const int mt = (blk >> 6) * 8 + (sub & 7);     // 0..511, mt%8 == blk%8 -> one XCD per m-tile
  const int m0 = mt * 128;
  const int tid = threadIdx.x;
  const int lane = tid & 63;
  const int wv = tid >> 6;

  f32x4 acc[2][8];
#pragma unroll
  for (int i = 0; i < 2; ++i)
#pragma unroll
    for (int j = 0; j < 8; ++j) acc[i][j] = (f32x4){0.f, 0.f, 0.f, 0.f};

  // staging: 16 rows per wave-instr, 4 lanes per 64B row; swizzled source chunk
  const int srow = wv * 32 + (lane >> 2);
  const int swz_st = (((lane & 3) ^ ((lane >> 3) & 3))) * 8;   // lane-constant
  const u16* gA = Ab + (size_t)(m0 + srow) * HID + swz_st;
  const int nn = srow;  // wave-uniform: waves 0,1 stage Wz cols, waves 2,3 Wh cols
  const int brow = (nn < 64) ? (hb * 64 + nn) : (448 + hb * 64 + nn);
  const u16* gB = Btw + (size_t)brow * HID + swz_st;

  // reader: chunk (lane>>4) of row r lives at slot (lane>>4) ^ ((r>>1)&3)
  const int rdoff = (((lane >> 4) ^ ((lane >> 1) & 3))) * 8;   // lane-constant

  for (int kk = 0; kk < HID; kk += 32) {
#pragma unroll
    for (int j = 0; j < 2; ++j) {
      gload_lds16(gA + (size_t)(j * 16) * HID + kk, &As[(wv * 32 + j * 16) * 32]);
      gload_lds16(gB + (size_t)(j * 16) * HID + kk, &Bs[(wv * 32 + j * 16) * 32]);
    }
    __syncthreads();
    bf16x8 af[2], bfr[8];
#pragma unroll
    for (int i = 0; i < 2; ++i)
      af[i] = *(const bf16x8*)&As[(wv * 32 + i * 16 + (lane & 15)) * 32 + rdoff];
#pragma unroll
    for (int j = 0; j < 8; ++j)
      bfr[j] = *(const bf16x8*)&Bs[(j * 16 + (lane & 15)) * 32 + rdoff];
#pragma unroll
    for (int i = 0; i < 2; ++i)
#pragma unroll
      for (int j = 0; j < 8; ++j)
        acc[i][j] = __builtin_amdgcn_mfma_f32_16x16x32_bf16(af[i], bfr[j], acc[i][j], 0, 0, 0);
    __syncthreads();
  }

  // epilogue: C/D layout col=lane&15, row=quad*4+reg. acc[i][jj]=k, acc[i][jj+4]=hh.
  const int col0 = hb * 64 + (lane & 15);
  const int quad = lane >> 4;
  float bzv[4], bhv[4];
#pragma unroll
  for (int jj = 0; jj < 4; ++jj) { bzv[jj] = bz[col0 + jj * 16]; bhv[jj] = bh[col0 + jj * 16]; }

  const int mrow = m0;           // wave wv owns rows [m0+wv*32, +32) = one scan chunk
  const int wrow = mrow + wv * 32;
  const int bb = wrow >> 11;
  const int cc = (wrow & 2047) >> 5;
  const size_t abase = ((size_t)(bb * CHUNKS + cc)) * HID;

#pragma unroll
  for (int jj = 0; jj < 4; ++jj) {
    float Aseg[2], Bseg[2];
#pragma unroll
    for (int i = 0; i < 2; ++i) {
      const int rbase = wrow + i * 16 + quad * 4;
      float A = 1.f, Bv = 0.f;
#pragma unroll
      for (int r = 0; r < 4; ++r) {
        float kv = acc[i][jj][r] + bzv[jj];
        float hv = acc[i][jj + 4][r] + bhv[jj];
        float e = __expf(-kv);
        float inv = fast_rcp(1.f + e);
        float a = e * inv;   // sigmoid(-k) = 1-z
        float v = inv * ((hv >= 0.f) ? (hv + 0.5f) : fast_rcp(1.f + __expf(-hv)));
        av[(size_t)(rbase + r) * HID + col0 + jj * 16] = f2bf(a) | (f2bf(v) << 16);
        A *= a;
        Bv = a * Bv + v;
      }
      Aseg[i] = A; Bseg[i] = Bv;
    }
#pragma unroll
    for (int i = 0; i < 2; ++i) {
      float Ap = __shfl_xor(Aseg[i], 16), Bp = __shfl_xor(Bseg[i], 16);
      float Ae = (quad & 1) ? Ap : Aseg[i], Be = (quad & 1) ? Bp : Bseg[i];
      float Al = (quad & 1) ? Aseg[i] : Ap, Bl = (quad & 1) ? Bseg[i] : Bp;
      Aseg[i] = Al * Ae; Bseg[i] = Al * Be + Bl;
      Ap = __shfl_xor(Aseg[i], 32); Bp = __shfl_xor(Bseg[i], 32);
      Ae = (quad & 2) ? Ap : Aseg[i]; Be = (quad & 2) ? Bp : Bseg[i];
      Al = (quad & 2) ? Aseg[i] : Ap; Bl = (quad & 2) ? Bseg[i] : Bp;
      Aseg[i] = Al * Ae; Bseg[i] = Al * Be + Bl;
    }
    float CA = Aseg[1] * Aseg[0];
    float CB = Aseg[1] * Bseg[0] + Bseg[1];
    if (quad == 0) {
      Ac[abase + col0 + jj * 16] = CA;
      Bc[abase + col0 + jj * 16] = CB;
    }
  }
}

// ---------------- phase 2: sequential over chunks; also emits h[T-1] (hiddens output)
__global__ __launch_bounds__(256) void scan_boundary(const float* __restrict__ Ac,
                                                     const float* __restrict__ Bc,
                                                     const float* __restrict__ h0,
                                                     float* __restrict__ hinit,
                                                     float* __restrict__ hid_out) {
  const int idx = blockIdx.x * 256 + threadIdx.x;  // b*HID + h
  const int b = idx >> 9, h = idx & 511;
  float x0 = h0[idx];
  float hr = (x0 >= 0.f) ? (x0 + 0.5f) : fast_rcp(1.f + __expf(-x0));  // g(h0)
  for (int c = 0; c < CHUNKS; ++c) {
    size_t o = ((size_t)(b * CHUNKS + c)) * HID + h;
    hinit[o] = hr;
    hr = Ac[o] * hr + Bc[o];
  }
  hid_out[idx] = hr;
}

// ---------------- phase 3: apply scan + LayerNorm + residual.
// Restructured: pass 1 (h-pinned) scans into 64KB fp32 LDS (no barriers); ONE barrier;
// pass 2 each wave owns 4 t-rows: b128 LDS reads + shfl reduce -> mu/rs in wave regs ->
// apply LN + residual + store (no broadcast, no further barriers).
__global__ __launch_bounds__(512) void scan_apply(const uint32_t* av,  // may alias outf
                                                  const float* __restrict__ hinit,
                                                  const u16* __restrict__ resb,
                                                  const float* __restrict__ gamma,
                                                  const float* __restrict__ beta,
                                                  u16* outb, float* outf) {
  __shared__ float hbuf[TC][HID];   // exactly 64 KB
  const int b = blockIdx.y, c = blockIdx.x, h = threadIdx.x;
  const int lane = h & 63, wv = h >> 6;
  const size_t rowbase = (size_t)(b * SEQ + c * TC) * HID;

  // pass 1: sequential scan along t, thread pinned to channel h
  float hr = hinit[((size_t)(b * CHUNKS + c)) * HID + h];
#pragma unroll 8
  for (int t = 0; t < TC; ++t) {
    uint32_t p = av[rowbase + (size_t)t * HID + h];
    hr = bf2f(p & 0xffffu) * hr + bf2f(p >> 16);
    hbuf[t][h] = hr;
  }
  __syncthreads();

  // pass 2: wave wv handles t = wv*4 + i; lane covers h = lane*8..lane*8+7
  const int h0c = lane * 8;
  const f32x4 gm0 = *(const f32x4*)&gamma[h0c];
  const f32x4 gm1 = *(const f32x4*)&gamma[h0c + 4];
  const f32x4 be0 = *(const f32x4*)&beta[h0c];
  const f32x4 be1 = *(const f32x4*)&beta[h0c + 4];
#pragma unroll
  for (int i = 0; i < 4; ++i) {
    const int t = wv * 4 + i;
    f32x4 v0 = *(const f32x4*)&hbuf[t][h0c];
    f32x4 v1 = *(const f32x4*)&hbuf[t][h0c + 4];
    float s = v0[0] + v0[1] + v0[2] + v0[3] + v1[0] + v1[1] + v1[2] + v1[3];
    float q = v0[0]*v0[0] + v0[1]*v0[1] + v0[2]*v0[2] + v0[3]*v0[3]
            + v1[0]*v1[0] + v1[1]*v1[1] + v1[2]*v1[2] + v1[3]*v1[3];
#pragma unroll
    for (int d = 32; d; d >>= 1) { s += __shfl_xor(s, d); q += __shfl_xor(q, d); }
    const float mu = s * (1.f / HID);
    const float rs = rsqrtf(q * (1.f / HID) - mu * mu + 1e-5f);
    // residual (bf16, 8 lanes' worth in 16B)
    const size_t o = rowbase + (size_t)t * HID + h0c;
    uint4 rr = *(const uint4*)(resb + o);
    float y[8];
    const uint32_t rw[4] = {rr.x, rr.y, rr.z, rr.w};
#pragma unroll
    for (int j = 0; j < 8; ++j) {
      float hv = (j < 4) ? v0[j] : v1[j - 4];
      float gmv = (j < 4) ? gm0[j] : gm1[j - 4];
      float bev = (j < 4) ? be0[j] : be1[j - 4];
      float rv = bf2f((rw[j >> 1] >> ((j & 1) * 16)) & 0xffffu);
      y[j] = (hv - mu) * rs * gmv + bev + rv;
    }
    if (outb) {
      uint4 ob;
      ob.x = f2bf(y[0]) | (f2bf(y[1]) << 16);
      ob.y = f2bf(y[2]) | (f2bf(y[3]) << 16);
      ob.z = f2bf(y[4]) | (f2bf(y[5]) << 16);
      ob.w = f2bf(y[6]) | (f2bf(y[7]) << 16);
      *(uint4*)(outb + o) = ob;
    }
    if (outf) {
      f32x4 o0 = {y[0], y[1], y[2], y[3]}, o1 = {y[4], y[5], y[6], y[7]};
      *(f32x4*)(outf + o) = o0;
      *(f32x4*)(outf + o + 4) = o1;
    }
  }
}

extern "C" void kernel_launch(void* const* d_in, const int* in_sizes, int n_in,
                              void* d_out, int out_size, void* d_ws, size_t ws_size,
                              hipStream_t stream) {
  (void)in_sizes; (void)n_in; (void)out_size; (void)ws_size;
  const float* x     = (const float*)d_in[0];
  const float* h0    = (const float*)d_in[1];
  const float* Wz    = (const float*)d_in[2];
  const float* bz    = (const float*)d_in[3];
  const float* Wh    = (const float*)d_in[4];
  const float* bh    = (const float*)d_in[5];
  const float* gamma = (const float*)d_in[6];
  const float* beta  = (const float*)d_in[7];

  float* outf = (float*)d_out;                   // [BT*HID] cur, then [L*B*H] hiddens
  uint32_t* av = (uint32_t*)d_out;               // alias: cur region free until last apply

  char* ws = (char*)d_ws;
  u16* curb = (u16*)ws;                                   size_t off = (size_t)BT * HID * 2;
  u16* Wt = (u16*)(ws + off);                             off += (size_t)NLAYERS * 1024 * HID * 2;
  float* Ac = (float*)(ws + off);                         off += (size_t)BATCH * CHUNKS * HID * 4;
  float* Bc = (float*)(ws + off);                         off += (size_t)BATCH * CHUNKS * HID * 4;
  float* hinit = (float*)(ws + off);                      // total ~80 MB

  hipLaunchKernelGGL(conv_weights, dim3(8, 16, NLAYERS), dim3(256), 0, stream, Wz, Wh, Wt);
  hipLaunchKernelGGL(conv_x, dim3(BT * HID / 1024), dim3(256), 0, stream, x, curb);

  for (int l = 0; l < NLAYERS; ++l) {
    const bool last = (l == NLAYERS - 1);
    hipLaunchKernelGGL(gemm_av, dim3(4096), dim3(256), 0, stream,
                       curb, Wt + (size_t)l * 1024 * HID, bz + l * HID, bh + l * HID,
                       av, Ac, Bc);
    hipLaunchKernelGGL(scan_boundary, dim3(BATCH * HID / 256), dim3(256), 0, stream,
                       Ac, Bc, h0 + (size_t)l * BATCH * HID, hinit,
                       outf + (size_t)BT * HID + (size_t)l * BATCH * HID);
    hipLaunchKernelGGL(scan_apply, dim3(CHUNKS, BATCH), dim3(512), 0, stream,
                       av, hinit, curb, gamma + l * HID, beta + l * HID,
                       last ? nullptr : curb, last ? outf : nullptr);
  }
}